// Round 1
// baseline (807.794 us; speedup 1.0000x reference)
//
#include <hip/hip_runtime.h>
#include <hip/hip_bf16.h>
#include <limits.h>

#define NUM_NODES 100000
#define OUT_CH 64
#define NUM_EDGES 3200000

// ---------- K1: min of edge_index[0] ----------
__global__ void LINK_62689342652831_min_kernel(const int* __restrict__ rows, int n,
                                               int* __restrict__ minp) {
    int tid = blockIdx.x * blockDim.x + threadIdx.x;
    int stride = gridDim.x * blockDim.x;
    int m = INT_MAX;
    for (int i = tid; i < n; i += stride) m = min(m, rows[i]);
    for (int off = 32; off > 0; off >>= 1) m = min(m, __shfl_xor(m, off, 64));
    if ((threadIdx.x & 63) == 0) atomicMin(minp, m);
}

// ---------- K2: transpose W [64][N] -> Wt [N][64] ----------
__global__ void LINK_62689342652831_transpose_kernel(const float* __restrict__ W,
                                                     float* __restrict__ Wt) {
    __shared__ float tile[64][65];
    int n0 = blockIdx.x * 64;
    int tx = threadIdx.x & 63;
    int ty = threadIdx.x >> 6;  // 0..3
    for (int c = ty; c < 64; c += 4) {
        int n = n0 + tx;
        tile[c][tx] = (n < NUM_NODES) ? W[(size_t)c * NUM_NODES + n] : 0.0f;
    }
    __syncthreads();
    for (int i = ty; i < 64; i += 4) {
        int n = n0 + i;
        if (n < NUM_NODES) Wt[(size_t)n * 64 + tx] = tile[tx][i];
    }
}

// ---------- K3: scatter-add, one wave per edge, lane = channel ----------
template <int USE_WT>
__global__ void LINK_62689342652831_scatter_kernel(const int* __restrict__ rows,
                                                   const int* __restrict__ cols,
                                                   const float* __restrict__ Wsrc,
                                                   const int* __restrict__ minp,
                                                   float* __restrict__ out) {
    int lane = threadIdx.x & 63;
    int gw = (blockIdx.x * blockDim.x + threadIdx.x) >> 6;
    int nw = (gridDim.x * blockDim.x) >> 6;
    int minv = *minp;
    for (int e = gw; e < NUM_EDGES; e += nw) {
        int r = rows[e] - minv;
        int c = cols[e];
        float v = USE_WT ? Wsrc[(size_t)c * 64 + lane]
                         : Wsrc[(size_t)lane * NUM_NODES + c];
        unsafeAtomicAdd(&out[(size_t)r * 64 + lane], v);
    }
}

// ---------- K4: wave-per-row log_softmax (in-place on out) ----------
__global__ void LINK_62689342652831_logsoftmax_kernel(float* __restrict__ out,
                                                      const float* __restrict__ bias) {
    int lane = threadIdx.x & 63;
    int gw = (blockIdx.x * blockDim.x + threadIdx.x) >> 6;
    int nw = (gridDim.x * blockDim.x) >> 6;
    float b = bias[lane];
    for (int r = gw; r < NUM_NODES; r += nw) {
        float x = out[(size_t)r * 64 + lane] + b;
        float m = x;
        for (int off = 32; off > 0; off >>= 1) m = fmaxf(m, __shfl_xor(m, off, 64));
        float e = expf(x - m);
        float s = e;
        for (int off = 32; off > 0; off >>= 1) s += __shfl_xor(s, off, 64);
        out[(size_t)r * 64 + lane] = x - m - logf(s);
    }
}

extern "C" void kernel_launch(void* const* d_in, const int* in_sizes, int n_in,
                              void* d_out, int out_size, void* d_ws, size_t ws_size,
                              hipStream_t stream) {
    const int* edges = (const int*)d_in[0];
    const int* rows = edges;
    const int* cols = edges + NUM_EDGES;
    const float* W = (const float*)d_in[1];
    const float* bias = (const float*)d_in[2];
    float* out = (float*)d_out;

    int* minp = (int*)d_ws;
    float* Wt = (float*)((char*)d_ws + 256);
    size_t wt_bytes = (size_t)NUM_NODES * 64 * sizeof(float);
    bool use_wt = ws_size >= 256 + wt_bytes;

    // zero the accumulator (d_out) and init min to a huge positive int (0x7f7f7f7f)
    hipMemsetAsync(d_out, 0, (size_t)out_size * sizeof(float), stream);
    hipMemsetAsync(minp, 0x7f, sizeof(int), stream);

    LINK_62689342652831_min_kernel<<<2048, 256, 0, stream>>>(rows, NUM_EDGES, minp);

    if (use_wt) {
        LINK_62689342652831_transpose_kernel<<<(NUM_NODES + 63) / 64, 256, 0, stream>>>(W, Wt);
        LINK_62689342652831_scatter_kernel<1><<<2048, 256, 0, stream>>>(rows, cols, Wt, minp, out);
    } else {
        LINK_62689342652831_scatter_kernel<0><<<2048, 256, 0, stream>>>(rows, cols, W, minp, out);
    }

    LINK_62689342652831_logsoftmax_kernel<<<4096, 256, 0, stream>>>(out, bias);
}